// Round 12
// baseline (184.938 us; speedup 1.0000x reference)
//
#include <hip/hip_runtime.h>

#define NT 256
#define RCHUNK 64
#define NSLOT 32
#define PSTRIDE 80   // f2 slots per slab row (max 64+2*ST=72, padded)

typedef float f2 __attribute__((ext_vector_type(2)));
typedef float f4 __attribute__((ext_vector_type(4)));

__device__ __forceinline__ float ccval(float sI, float sJ, float sII, float sJJ,
                                       float sIJ, float inv_ws) {
    float cross = fmaf(-(sI * sJ), inv_ws, sIJ);
    float iv    = fmaf(-(sI * sI), inv_ws, sII);
    float jv    = fmaf(-(sJ * sJ), inv_ws, sJJ);
    float den   = fmaf(iv, jv, 1e-8f);
    return (cross * cross) * __builtin_amdgcn_rcpf(den);
}

// masked aligned pair load: cols cp,cp+1 (cp even, W even -> never straddles)
__device__ __forceinline__ f2 loadpair(const float* rowp, int cp, int W, bool rv) {
    bool in = rv && ((unsigned)cp < (unsigned)W);
    int ca = in ? cp : 0;
    f2 v = *(const f2*)(rowp + ca);
    if (!in) { v.x = 0.f; v.y = 0.f; }
    return v;
}

// Wave-autonomous batched pipeline. Wave owns 64 cols x RCHUNK rows.
// Batch = WIN rows: {issue global batch k+1} {compute batch k from LDS}
// {ds_write batch k+1} {0-instr wavefront fence}. Ring slot = u (literal).
template<int W, int WIN, int S, bool PRE>
__device__ void level_wave(const float* __restrict__ Jbase,
                           const float* __restrict__ Ibase,
                           const float* __restrict__ ybase,
                           int sub, float* __restrict__ ws_acc, int level,
                           f2* __restrict__ slab, int wid)
{
    constexpr int HW = WIN / 2;
    constexpr int ST = (HW + 1) & ~1;        // staging left-extent (even)
    constexpr int D  = ST - HW;              // tap index shift
    constexpr int NPAIRS = 32 + ST;          // col-pairs staged per row
    constexpr int T  = RCHUNK + 2 * HW;
    constexpr int NB = (T + WIN - 1) / WIN;
    constexpr int OFF = (S - 2) / 2;
    constexpr float INV_WS = 1.0f / (float)(WIN * WIN);
    constexpr int STRIPS = W / 64;
    constexpr int CHUNKS = W / RCHUNK;

    int b     = sub / (STRIPS * CHUNKS);
    int rem   = sub - b * (STRIPS * CHUNKS);
    int chunk = rem / STRIPS;
    int strip = rem - chunk * STRIPS;
    int r0 = chunk * RCHUNK;
    int c0 = strip * 64;

    const float* Jb = Jbase + (size_t)b * W * W;
    const float* Ib = Ibase + (size_t)b * W * W;       // PRE (or S==1)
    const float* Yb = ybase + (size_t)b * 512 * 512;   // !PRE, S>1

    int l = threadIdx.x & 63;
    int cp = c0 - ST + 2 * l;                 // even; loop-invariant
    bool act = l < NPAIRS;

    f2 stJ[WIN], stI[WIN];
    float rI[WIN], rJ[WIN], rII[WIN], rJJ[WIN], rIJ[WIN];
#pragma unroll
    for (int k = 0; k < WIN; ++k) {
        rI[k]=0.f; rJ[k]=0.f; rII[k]=0.f; rJJ[k]=0.f; rIJ[k]=0.f;
        stJ[k].x=0.f; stJ[k].y=0.f; stI[k].x=0.f; stI[k].y=0.f;
    }
    float vI=0.f, vJ=0.f, vII=0.f, vJJ=0.f, vIJ=0.f;
    float l2acc = 0.f, ccacc = 0.f;

    auto fetch_batch = [&](int k) {
#pragma unroll
        for (int u = 0; u < WIN; ++u) {
            int rr = k * WIN + u;
            int r  = r0 - HW + rr;
            bool rv = (rr < T) && (r >= 0) && (r < W);
            int rc = __builtin_amdgcn_readfirstlane(rv ? r : 0);
            if (act) {
                stJ[u] = loadpair(Jb + (size_t)rc * W, cp, W, rv);
                if constexpr (PRE || S == 1) {
                    stI[u] = loadpair(Ib + (size_t)rc * W, cp, W, rv);
                } else {
                    // fallback: direct 2x2 downsample from y (slow, correct)
                    float i0 = 0.f, i1 = 0.f;
                    if (rv && (unsigned)cp < (unsigned)W) {
                        int yr = S * rc + OFF;
                        const float* pa = Yb + (size_t)yr * 512;
                        const float* pb = pa + 512;
                        int c = S * cp + OFF;
                        i0 = 0.25f * ((pa[c] + pa[c+1]) + (pb[c] + pb[c+1]));
                        int c1 = c + S;
                        i1 = 0.25f * ((pa[c1] + pa[c1+1]) + (pb[c1] + pb[c1+1]));
                    }
                    stI[u].x = i0; stI[u].y = i1;
                }
            }
        }
    };

    auto write_batch = [&](int k) {
#pragma unroll
        for (int u = 0; u < WIN; ++u) {
            if (act) {
                f4 w; w.x = stI[u].x; w.y = stJ[u].x; w.z = stI[u].y; w.w = stJ[u].y;
                f2* row = slab + (size_t)(((k & 1) * WIN + u) * PSTRIDE);
                *(f4*)(row + 2 * l) = w;      // 16B-aligned ds_write_b128
            }
        }
    };

    fetch_batch(0);
    write_batch(0);
    __builtin_amdgcn_fence(__ATOMIC_ACQ_REL, "wavefront");

    for (int k = 0; k < NB; ++k) {
        if (k + 1 < NB) fetch_batch(k + 1);   // in flight across whole batch
        // ---- compute batch k from LDS ----
#pragma unroll
        for (int u = 0; u < WIN; ++u) {
            int rr = k * WIN + u;
            if (rr < T) {                      // wave-uniform
                const f2* row = slab + (size_t)(((k & 1) * WIN + u) * PSTRIDE);
                float sI=0.f, sJ=0.f, sII=0.f, sJJ=0.f, sIJ=0.f, Ic=0.f, Jc=0.f;
#pragma unroll
                for (int kk = 0; kk < WIN; ++kk) {
                    f2 q = row[l + kk + D];    // {I,J} pair; merges to ds_read2_b64
                    if (kk == HW) { Ic = q.x; Jc = q.y; }
                    sI += q.x; sJ += q.y;
                    sII = fmaf(q.x, q.x, sII);
                    sJJ = fmaf(q.y, q.y, sJJ);
                    sIJ = fmaf(q.x, q.y, sIJ);
                }
                if (rr >= HW && rr < HW + RCHUNK) {
                    float d = Jc - Ic;
                    l2acc = fmaf(d, d, l2acc);
                }
                rI[u]=sI; rJ[u]=sJ; rII[u]=sII; rJJ[u]=sJJ; rIJ[u]=sIJ;
                vI+=sI; vJ+=sJ; vII+=sII; vJJ+=sJJ; vIJ+=sIJ;
                if (rr >= 2 * HW) {
                    ccacc += ccval(vI, vJ, vII, vJJ, vIJ, INV_WS);
                    const int uo = (u + 1) % WIN;   // literal after unroll
                    vI-=rI[uo]; vJ-=rJ[uo]; vII-=rII[uo]; vJJ-=rJJ[uo]; vIJ-=rIJ[uo];
                }
            }
        }
        if (k + 1 < NB) {
            write_batch(k + 1);                // waits its loads here (hidden)
            __builtin_amdgcn_fence(__ATOMIC_ACQ_REL, "wavefront");
        }
    }

#pragma unroll
    for (int off = 32; off > 0; off >>= 1) {
        l2acc += __shfl_down(l2acc, off);
        ccacc += __shfl_down(ccacc, off);
    }
    if (l == 0) {
        int slot = wid & (NSLOT - 1);
        atomicAdd(&ws_acc[(level * 2 + 0) * NSLOT + slot], l2acc);
        atomicAdd(&ws_acc[(level * 2 + 1) * NSLOT + slot], ccacc);
    }
}

template<bool PRE>
__global__ __launch_bounds__(NT)
void hier_loss_kernel(const float* __restrict__ yh0, const float* __restrict__ yh1,
                      const float* __restrict__ yh2, const float* __restrict__ yh3,
                      const float* __restrict__ y,
                      const float* __restrict__ Y1, const float* __restrict__ Y2,
                      const float* __restrict__ Y3, float* ws_acc)
{
    __shared__ f2 slab[4][2][9][PSTRIDE];   // 46080 B
    int wave = threadIdx.x >> 6;
    f2* sl = &slab[wave][0][0][0];
    int bid = blockIdx.x;
    int wid = bid * 4 + wave;
    // L0: 512 blocks (2048 waves) | L1: 128 blk | L2: 32 blk | L3: 8 blk = 680
    if (bid < 512) {
        level_wave<512, 9, 1, PRE>(yh0, y,  y, wid,        ws_acc, 0, sl, wid);
    } else if (bid < 640) {
        level_wave<256, 9, 2, PRE>(yh1, Y1, y, wid - 2048, ws_acc, 1, sl, wid);
    } else if (bid < 672) {
        level_wave<128, 7, 4, PRE>(yh2, Y2, y, wid - 2560, ws_acc, 2, sl, wid);
    } else {
        level_wave<64,  5, 8, PRE>(yh3, Y3, y, wid - 2688, ws_acc, 3, sl, wid);
    }
}

__global__ void downsample_kernel(const float* __restrict__ y,
                                  float* __restrict__ Y1, float* __restrict__ Y2,
                                  float* __restrict__ Y3)
{
    const int n1 = 32 * 256 * 256, n2 = 32 * 128 * 128, n3 = 32 * 64 * 64;
    int stride = gridDim.x * blockDim.x;
    for (int i = blockIdx.x * blockDim.x + threadIdx.x; i < n1 + n2 + n3; i += stride) {
        if (i < n1) {
            int b = i >> 16, rc = i & 65535, r = rc >> 8, c = rc & 255;
            const float* p = y + ((size_t)b * 512 + 2 * r) * 512 + 2 * c;
            f2 a = *(const f2*)p; f2 d = *(const f2*)(p + 512);
            Y1[i] = 0.25f * ((a.x + a.y) + (d.x + d.y));
        } else if (i < n1 + n2) {
            int j = i - n1;
            int b = j >> 14, rc = j & 16383, r = rc >> 7, c = rc & 127;
            const float* p = y + ((size_t)b * 512 + 4 * r + 1) * 512 + 4 * c + 1;
            Y2[j] = 0.25f * ((p[0] + p[1]) + (p[512] + p[513]));
        } else {
            int j = i - n1 - n2;
            int b = j >> 12, rc = j & 4095, r = rc >> 6, c = rc & 63;
            const float* p = y + ((size_t)b * 512 + 8 * r + 3) * 512 + 8 * c + 3;
            Y3[j] = 0.25f * ((p[0] + p[1]) + (p[512] + p[513]));
        }
    }
}

__global__ void hier_finalize_kernel(const float* __restrict__ ws_acc, float* __restrict__ out)
{
    if (threadIdx.x == 0 && blockIdx.x == 0) {
        const float wts[4] = {1.0f, 0.5f, 0.25f, 0.125f};
        float total = 0.f;
#pragma unroll
        for (int lv = 0; lv < 4; ++lv) {
            float l2s = 0.f, ccs = 0.f;
            for (int s = 0; s < NSLOT; ++s) {
                l2s += ws_acc[(lv * 2 + 0) * NSLOT + s];
                ccs += ws_acc[(lv * 2 + 1) * NSLOT + s];
            }
            float l2  = l2s / 32.0f;
            float ncc = -ccs / (32.0f * 100.0f);
            float ll  = wts[lv] * (l2 + ncc) * 0.5f;
            out[1 + lv] = ll;
            total += ll;
        }
        out[0] = total;
    }
}

extern "C" void kernel_launch(void* const* d_in, const int* in_sizes, int n_in,
                              void* d_out, int out_size, void* d_ws, size_t ws_size,
                              hipStream_t stream)
{
    const float* yh0 = (const float*)d_in[0];
    const float* yh1 = (const float*)d_in[1];
    const float* yh2 = (const float*)d_in[2];
    const float* yh3 = (const float*)d_in[3];
    const float* y   = (const float*)d_in[4];
    float* ws_acc = (float*)d_ws;
    float* Y1 = ws_acc + 256;
    float* Y2 = Y1 + 32 * 256 * 256;
    float* Y3 = Y2 + 32 * 128 * 128;
    float* out = (float*)d_out;

    const size_t NEED = (size_t)(256 + 32 * (256 * 256 + 128 * 128 + 64 * 64)) * 4;
    hipMemsetAsync(ws_acc, 0, 256 * sizeof(float), stream);
    if (ws_size >= NEED) {
        downsample_kernel<<<2048, 256, 0, stream>>>(y, Y1, Y2, Y3);
        hier_loss_kernel<true><<<680, NT, 0, stream>>>(yh0, yh1, yh2, yh3, y, Y1, Y2, Y3, ws_acc);
    } else {
        hier_loss_kernel<false><<<680, NT, 0, stream>>>(yh0, yh1, yh2, yh3, y, Y1, Y2, Y3, ws_acc);
    }
    hier_finalize_kernel<<<1, 64, 0, stream>>>(ws_acc, out);
}